// Round 3
// baseline (371.425 us; speedup 1.0000x reference)
//
#include <hip/hip_runtime.h>

// Problem constants (from reference)
constexpr int B = 4, N = 1024, M = 64, H = 32, W = 32;
constexpr int HW = H * W;                       // 1024
constexpr size_t S = (size_t)B * N * HW;        // per-channel plane stride = 4,194,304 floats
constexpr float EXPAND   = 1.2f;
constexpr float TWO_SIG2 = 2.0f * 1.6f * 1.6f;  // 5.12
constexpr float THR2 = 0.6f;                    // GAUSS_THR
constexpr float THR3 = 0.5f;                    // GAUSS_3D_THR == GAUSS_DEPTH_THR

// native vector type for __builtin_nontemporal_store
typedef float vfloat4 __attribute__((ext_vector_type(4)));

// 20 output channel-planes, flat concat in reference return order.
// Plane p -> (mode, baseS, k, c): dst = baseS*S + (bn*k + c)*HW + cell
// modes: 0=a*f3  1=offx*f2  2=offy*f2  3=offx*f3  4=offy*f3  5=f2  6=cls  7=cls_w

__global__ __launch_bounds__(256)
void rcnn3d_plane_kernel(const float* __restrict__ boxes,     // (B,N,4)
                         const float* __restrict__ gt_boxes,  // (B,M,14)
                         const int*   __restrict__ pos_flag,  // (B,N)
                         const int*   __restrict__ gt_id,     // (B,N)
                         float* __restrict__ out)
{
    const int blk = blockIdx.x;
    const int p   = blk >> 12;        // plane index [0,20)
    const int bn  = blk & 4095;       // b*N + n
    const int b   = bn >> 10;
    const int tid = threadIdx.x;

    // ---- uniform per-plane params ----
    int mode, baseS, k, c;
    switch (p) {
        case 0:  mode=6; baseS=0;  k=1; c=0; break;  // cls_label
        case 1:  mode=7; baseS=1;  k=1; c=0; break;  // cls_label_w
        case 2:  mode=1; baseS=2;  k=2; c=0; break;  // reg_2d x
        case 3:  mode=2; baseS=2;  k=2; c=1; break;  // reg_2d y
        case 4:  mode=5; baseS=4;  k=2; c=0; break;  // reg_2d_w
        case 5:  mode=5; baseS=4;  k=2; c=1; break;
        case 6:  mode=3; baseS=6;  k=2; c=0; break;  // reg_3d x
        case 7:  mode=4; baseS=6;  k=2; c=1; break;  // reg_3d y
        case 8:  mode=0; baseS=8;  k=2; c=0; break;  // reg_3d_w
        case 9:  mode=0; baseS=8;  k=2; c=1; break;
        case 10: mode=0; baseS=10; k=1; c=0; break;  // depth_label   (a=depth)
        case 11: mode=0; baseS=11; k=1; c=0; break;  // depth_label_w
        case 12: mode=0; baseS=12; k=3; c=0; break;  // dim_label[0]  (a=dim0)
        case 13: mode=0; baseS=12; k=3; c=1; break;  // dim_label[1]  (a=dim1)
        case 14: mode=0; baseS=12; k=3; c=2; break;  // dim_label[2]  (a=dim2)
        case 15: mode=0; baseS=15; k=3; c=0; break;  // dim_label_w
        case 16: mode=0; baseS=15; k=3; c=1; break;
        case 17: mode=0; baseS=15; k=3; c=2; break;
        case 18: mode=0; baseS=18; k=1; c=0; break;  // rot_label     (a=rot)
        default: mode=0; baseS=19; k=1; c=0; break;  // rot_label_w
    }

    // ---- per-(b,n) block-uniform scalars (uniform addresses -> s_loads, L1-hot) ----
    const float4 bx = *reinterpret_cast<const float4*>(boxes + (size_t)bn * 4);
    const int   gid = gt_id[bn];
    const float* g  = gt_boxes + ((size_t)b * 64 + gid) * 14;
    const bool valid = (g[6] != 0.0f) && (pos_flag[bn] > 0);

    float a = 1.0f;
    if      (p == 10) a = g[12];   // depth
    else if (p == 12) a = g[7];    // dim0
    else if (p == 13) a = g[8];    // dim1
    else if (p == 14) a = g[9];    // dim2
    else if (p == 18) a = g[13];   // rot

    // replicate reference float-op order exactly (same as round-1 passing kernel)
    const float cx = 0.5f * (bx.x + bx.z);
    const float cy = 0.5f * (bx.y + bx.w);
    const float hw = 0.5f * (bx.z - bx.x) * EXPAND;
    const float hh = 0.5f * (bx.w - bx.y) * EXPAND;
    const float ex1 = cx - hw, ey1 = cy - hh;
    const float ex2 = cx + hw, ey2 = cy + hh;
    const float sx = (float)W / (ex2 - ex1 + 1.0f);
    const float sy = (float)H / (ey2 - ey1 + 1.0f);
    const float kx = (g[4] - ex1) * sx;
    const float ky = (g[5] - ey1) * sy;

    // ---- 4 consecutive cells (one row) per thread ----
    const int hrow = tid >> 3;
    const int w0   = (tid & 7) * 4;
    const float gy   = (float)hrow;
    const float offy = ky - gy;
    const float dy   = gy + 0.5f - ky;
    const float dy2  = dy * dy;

    float s4[4], ox4[4];
    bool  m2v[4], m3v[4];
    bool  any2 = false;
#pragma unroll
    for (int j = 0; j < 4; ++j) {
        const float gx = (float)(w0 + j);
        const float dx = gx + 0.5f - kx;
        const float s  = expf(-((dx * dx + dy2) / TWO_SIG2));
        s4[j]  = s;
        ox4[j] = kx - gx;
        m2v[j] = (s >= THR2) && valid;
        m3v[j] = (s >= THR3) && valid;
        any2  |= m2v[j];
    }

    // ---- block-wide any(m2), only for cls planes (uniform branch) ----
    bool has = false;
    if (mode >= 6) {
        __shared__ int s_has;
        if (tid == 0) s_has = 0;
        __syncthreads();
        if (any2) s_has = 1;
        __syncthreads();
        has = (s_has != 0);
    }

    // ---- assemble and store one contiguous float4 ----
    vfloat4 v;
#pragma unroll
    for (int j = 0; j < 4; ++j) {
        const float f2 = m2v[j] ? 1.0f : 0.0f;
        const float f3 = m3v[j] ? 1.0f : 0.0f;
        float val;
        switch (mode) {
            case 0:  val = a * f3;               break;
            case 1:  val = ox4[j] * f2;          break;
            case 2:  val = offy * f2;            break;
            case 3:  val = ox4[j] * f3;          break;
            case 4:  val = offy * f3;            break;
            case 5:  val = f2;                   break;
            case 6:  val = has ? s4[j] : -1.0f;  break;
            default: val = has ? 1.0f : 0.0f;    break;
        }
        v[j] = val;
    }

    float* dst = out + (size_t)baseS * S + ((size_t)bn * k + c) * HW + (size_t)tid * 4;
    __builtin_nontemporal_store(v, reinterpret_cast<vfloat4*>(dst));
}

extern "C" void kernel_launch(void* const* d_in, const int* in_sizes, int n_in,
                              void* d_out, int out_size, void* d_ws, size_t ws_size,
                              hipStream_t stream) {
    const float* boxes    = (const float*)d_in[0];
    const float* gt_boxes = (const float*)d_in[1];
    const int*   pos_flag = (const int*)d_in[2];
    const int*   gt_id    = (const int*)d_in[3];
    float*       out      = (float*)d_out;

    rcnn3d_plane_kernel<<<dim3(20 * 4096), dim3(256), 0, stream>>>(
        boxes, gt_boxes, pos_flag, gt_id, out);
}

// Round 4
// 369.663 us; speedup vs baseline: 1.0048x; 1.0048x over previous
//
#include <hip/hip_runtime.h>

// Problem constants (from reference)
constexpr int B = 4, N = 1024, M = 64, H = 32, W = 32;
constexpr int HW = H * W;                       // 1024
constexpr size_t S = (size_t)B * N * HW;        // per-channel plane stride (floats)
constexpr float EXPAND   = 1.2f;
constexpr float TWO_SIG2 = 2.0f * 1.6f * 1.6f;  // 5.12
constexpr float THR2 = 0.6f;                    // GAUSS_THR
constexpr float THR3 = 0.5f;                    // GAUSS_3D_THR == GAUSS_DEPTH_THR
constexpr int CHUNK = 8;                        // bn per writer block
constexpr int CHUNKS_PER_PLANE = (B * N) / CHUNK;  // 512

// ---- shared per-bn setup: identical float-op order to the passing round-1 kernel ----
__device__ __forceinline__ void bn_setup(const float* __restrict__ boxes,
                                         const float* __restrict__ gt_boxes,
                                         const int*   __restrict__ pos_flag,
                                         const int*   __restrict__ gt_id,
                                         int bn, int b,
                                         float& kx, float& ky, bool& valid,
                                         const float*& g)
{
    const float4 bx = *reinterpret_cast<const float4*>(boxes + (size_t)bn * 4);
    const int gid = gt_id[bn];
    g = gt_boxes + ((size_t)b * M + gid) * 14;
    valid = (g[6] != 0.0f) && (pos_flag[bn] > 0);

    const float cx = 0.5f * (bx.x + bx.z);
    const float cy = 0.5f * (bx.y + bx.w);
    const float hw = 0.5f * (bx.z - bx.x) * EXPAND;
    const float hh = 0.5f * (bx.w - bx.y) * EXPAND;
    const float ex1 = cx - hw, ey1 = cy - hh;
    const float ex2 = cx + hw, ey2 = cy + hh;
    const float sx = (float)W / (ex2 - ex1 + 1.0f);
    const float sy = (float)H / (ey2 - ey1 + 1.0f);
    kx = (g[4] - ex1) * sx;
    ky = (g[5] - ey1) * sy;
}

// identical score expression in both kernels (bit-identical mask decisions)
__device__ __forceinline__ float cell_score(float kx, float dy2, int gx)
{
    const float dx = (float)gx + 0.5f - kx;
    return expf(-((dx * dx + dy2) / TWO_SIG2));
}

// ---- Kernel A: per-bn `has` flag (one wave per bn) ----
__global__ __launch_bounds__(256)
void has_kernel(const float* __restrict__ boxes,
                const float* __restrict__ gt_boxes,
                const int*   __restrict__ pos_flag,
                const int*   __restrict__ gt_id,
                int* __restrict__ has_out)
{
    const int wave = threadIdx.x >> 6;
    const int lane = threadIdx.x & 63;
    const int bn   = blockIdx.x * 4 + wave;     // grid = 1024 blocks
    const int b    = bn >> 10;

    float kx, ky; bool valid; const float* g;
    bn_setup(boxes, gt_boxes, pos_flag, gt_id, bn, b, kx, ky, valid, g);

    bool any2 = false;
#pragma unroll
    for (int i = 0; i < 16; ++i) {
        const int cell = lane * 16 + i;         // 64 lanes x 16 cells = 1024
        const int gy = cell >> 5, gx = cell & 31;
        const float dy  = (float)gy + 0.5f - ky;
        const float dy2 = dy * dy;
        any2 |= (cell_score(kx, dy2, gx) >= THR2);
    }
    any2 = __any(any2);
    if (lane == 0) has_out[bn] = (any2 && valid) ? 1 : 0;
}

// ---- Kernel B: plane-sequential writer ----
// modes: 0=a*f3  1=offx*f2  2=offy*f2  3=offx*f3  4=offy*f3  5=f2  6=cls  7=cls_w
__global__ __launch_bounds__(256)
void writer_kernel(const float* __restrict__ boxes,
                   const float* __restrict__ gt_boxes,
                   const int*   __restrict__ pos_flag,
                   const int*   __restrict__ gt_id,
                   const int*   __restrict__ hasv,
                   float* __restrict__ out)
{
    const int blk   = blockIdx.x;
    const int p     = blk >> 9;                 // plane [0,20), 512 chunks/plane
    const int chunk = blk & (CHUNKS_PER_PLANE - 1);
    const int bn0   = chunk * CHUNK;
    const int tid   = threadIdx.x;

    // per-plane uniform params
    int mode, baseS, k, c, aoff;
    switch (p) {
        case 0:  mode=6; baseS=0;  k=1; c=0; aoff=-1; break;  // cls_label
        case 1:  mode=7; baseS=1;  k=1; c=0; aoff=-1; break;  // cls_label_w
        case 2:  mode=1; baseS=2;  k=2; c=0; aoff=-1; break;  // reg_2d x
        case 3:  mode=2; baseS=2;  k=2; c=1; aoff=-1; break;  // reg_2d y
        case 4:  mode=5; baseS=4;  k=2; c=0; aoff=-1; break;  // reg_2d_w
        case 5:  mode=5; baseS=4;  k=2; c=1; aoff=-1; break;
        case 6:  mode=3; baseS=6;  k=2; c=0; aoff=-1; break;  // reg_3d x
        case 7:  mode=4; baseS=6;  k=2; c=1; aoff=-1; break;  // reg_3d y
        case 8:  mode=0; baseS=8;  k=2; c=0; aoff=-1; break;  // reg_3d_w (a=1)
        case 9:  mode=0; baseS=8;  k=2; c=1; aoff=-1; break;
        case 10: mode=0; baseS=10; k=1; c=0; aoff=12; break;  // depth_label
        case 11: mode=0; baseS=11; k=1; c=0; aoff=-1; break;  // depth_label_w
        case 12: mode=0; baseS=12; k=3; c=0; aoff=7;  break;  // dim_label[0]
        case 13: mode=0; baseS=12; k=3; c=1; aoff=8;  break;  // dim_label[1]
        case 14: mode=0; baseS=12; k=3; c=2; aoff=9;  break;  // dim_label[2]
        case 15: mode=0; baseS=15; k=3; c=0; aoff=-1; break;  // dim_label_w
        case 16: mode=0; baseS=15; k=3; c=1; aoff=-1; break;
        case 17: mode=0; baseS=15; k=3; c=2; aoff=-1; break;
        case 18: mode=0; baseS=18; k=1; c=0; aoff=13; break;  // rot_label
        default: mode=0; baseS=19; k=1; c=0; aoff=-1; break;  // rot_label_w
    }

    const int hrow = tid >> 3;
    const int w0   = (tid & 7) * 4;
    float* const planeBase = out + (size_t)baseS * S + (size_t)c * HW + (size_t)tid * 4;

#pragma unroll
    for (int i = 0; i < CHUNK; ++i) {
        const int bn = bn0 + i;
        const int b  = bn >> 10;

        float kx, ky; bool valid; const float* g;
        bn_setup(boxes, gt_boxes, pos_flag, gt_id, bn, b, kx, ky, valid, g);

        const float a   = (aoff >= 0) ? g[aoff] : 1.0f;
        const bool  has = (mode >= 6) ? (hasv[bn] != 0) : false;

        const float gy   = (float)hrow;
        const float offy = ky - gy;
        const float dy   = gy + 0.5f - ky;
        const float dy2  = dy * dy;

        float4 v;
#pragma unroll
        for (int j = 0; j < 4; ++j) {
            const int gx = w0 + j;
            const float s  = cell_score(kx, dy2, gx);
            const float f2 = ((s >= THR2) && valid) ? 1.0f : 0.0f;
            const float f3 = ((s >= THR3) && valid) ? 1.0f : 0.0f;
            const float offx = kx - (float)gx;
            float val;
            switch (mode) {
                case 0:  val = a * f3;              break;
                case 1:  val = offx * f2;           break;
                case 2:  val = offy * f2;           break;
                case 3:  val = offx * f3;           break;
                case 4:  val = offy * f3;           break;
                case 5:  val = f2;                  break;
                case 6:  val = has ? s : -1.0f;     break;
                default: val = has ? 1.0f : 0.0f;   break;
            }
            (&v.x)[j] = val;
        }

        *reinterpret_cast<float4*>(planeBase + (size_t)bn * k * HW) = v;
    }
}

extern "C" void kernel_launch(void* const* d_in, const int* in_sizes, int n_in,
                              void* d_out, int out_size, void* d_ws, size_t ws_size,
                              hipStream_t stream) {
    const float* boxes    = (const float*)d_in[0];
    const float* gt_boxes = (const float*)d_in[1];
    const int*   pos_flag = (const int*)d_in[2];
    const int*   gt_id    = (const int*)d_in[3];
    float*       out      = (float*)d_out;
    int*         hasbuf   = (int*)d_ws;         // 4096 ints = 16 KB

    has_kernel<<<dim3((B * N) / 4), dim3(256), 0, stream>>>(
        boxes, gt_boxes, pos_flag, gt_id, hasbuf);

    writer_kernel<<<dim3(20 * CHUNKS_PER_PLANE), dim3(256), 0, stream>>>(
        boxes, gt_boxes, pos_flag, gt_id, hasbuf, out);
}